// Round 2
// baseline (592.347 us; speedup 1.0000x reference)
//
#include <hip/hip_runtime.h>
#include <hip/hip_bf16.h>

#define S_LEN 1024
#define BATCH 2048
#define HID   64
#define MB    4               // batch rows per block
#define NBLK  (BATCH / MB)    // 512 blocks -> 2 per CU
#define NTHR  (MB * HID)      // 256 threads = 4 waves

typedef _Float16 half8 __attribute__((ext_vector_type(8)));
typedef float    f32x4 __attribute__((ext_vector_type(4)));

#define L2E 1.4426950408889634f
#define HSTRIDE 72            // h rows stride (halves): byte stride 144 -> even 8-lane/4-bank spread
#define SSTRIDE 20            // scratch per-unit stride (floats): 16B-aligned, bank-even

__global__ __launch_bounds__(NTHR) void lstm_kernel(
    const float* __restrict__ x,      // (S, BATCH)
    const float* __restrict__ W_ih,   // (256,1)
    const float* __restrict__ W_hh,   // (256,64)
    const float* __restrict__ b_ih,   // (256,)
    const float* __restrict__ b_hh,   // (256,)
    const float* __restrict__ fc1_w,  // (128,64)
    const float* __restrict__ fc1_b,  // (128,)
    const float* __restrict__ fc2_w,  // (5,128)
    const float* __restrict__ fc2_b,  // (5,)
    float* __restrict__ out)          // (BATCH,5)
{
    // h double-buffered (fp16, 16 rows x HSTRIDE; rows 4..15 pad for M=16 tile)
    __shared__ __align__(16) _Float16 h_buf[2][16 * HSTRIDE];      // 4608 B
    // wave-private gate scratch: 4 waves x 16 units x SSTRIDE floats  (5120 B)
    __shared__ __align__(16) float scratch[4 * 16 * SSTRIDE];

    const int tid  = threadIdx.x;
    const int lane = tid & 63;
    const int wave = tid >> 6;        // 0..3
    const int l15  = lane & 15;
    const int quad = lane >> 4;       // 0..3
    const int b0   = blockIdx.x * MB;

    // ---- zero both h buffers (h0 = 0; pad rows stay 0 forever) ----
    {
        unsigned* hz = (unsigned*)&h_buf[0][0];
        for (int i = tid; i < 2 * 16 * HSTRIDE / 2; i += NTHR) hz[i] = 0u;
    }

    // ---- stationary W_hh fragments, per-wave column permutation ----
    // wave w, tile g (= gate), frag col n=l15 <-> W_hh row g*64 + 16w + n.
    // B-frag (16x16x32 f16): lane holds B[k=quad*8+j][n=l15] = W_hh[row][k], k-tile kt adds 32.
    // Pre-scaled by -log2e (sigmoid) / -2log2e (tanh, g gate) for exp2-based activations.
    half8 wfrag[4][2];
    #pragma unroll
    for (int g = 0; g < 4; ++g) {
        const float s = (g == 2) ? (-2.0f * L2E) : (-L2E);
        const float* wr = W_hh + (g * 64 + 16 * wave + l15) * HID + quad * 8;
        #pragma unroll
        for (int kt = 0; kt < 2; ++kt) {
            half8 f;
            #pragma unroll
            for (int j = 0; j < 8; ++j) f[j] = (_Float16)(wr[kt * 32 + j] * s);
            wfrag[g][kt] = f;
        }
    }

    // ---- elementwise ownership: thread (quad,l15) handles b=quad, u=16*wave+l15 ----
    const int u = 16 * wave + l15;
    float wih_s[4], bias_s[4];
    #pragma unroll
    for (int g = 0; g < 4; ++g) {
        const int n = g * 64 + u;
        const float s = (g == 2) ? (-2.0f * L2E) : (-L2E);
        wih_s[g]  = W_ih[n] * s;
        bias_s[g] = (b_ih[n] + b_hh[n]) * s;
    }

    float* scr_w = scratch + wave * 16 * SSTRIDE;   // wave-private region

    const float* xcol = x + b0 + quad;   // this thread's batch row
    float xcur = xcol[0];
    float c = 0.0f;
    int p = 0;

    __syncthreads();

    for (int s = 0; s < S_LEN; ++s) {
        // ---- MFMA: gates for this wave's 16 units, all 4 batch rows ----
        const _Float16* hb = &h_buf[p][0];
        const _Float16* arow = hb + l15 * HSTRIDE + quad * 8;
        half8 a0 = *(const half8*)(arow);        // k 0..31
        half8 a1 = *(const half8*)(arow + 32);   // k 32..63

        f32x4 acc[4];
        #pragma unroll
        for (int g = 0; g < 4; ++g) {
            f32x4 a = {0.f, 0.f, 0.f, 0.f};
            a = __builtin_amdgcn_mfma_f32_16x16x32_f16(a0, wfrag[g][0], a, 0, 0, 0);
            a = __builtin_amdgcn_mfma_f32_16x16x32_f16(a1, wfrag[g][1], a, 0, 0, 0);
            acc[g] = a;
        }

        float xn = 0.0f;
        if (s + 1 < S_LEN) xn = xcol[(size_t)(s + 1) * BATCH];  // prefetch

        // ---- acc -> wave-private scratch (no barrier; same-wave lgkmcnt) ----
        // C-layout: row = quad*4 + r (valid rows 0..3 => quad 0), col = l15 (unit).
        // scratch idx = u_local*SSTRIDE + 4*r + g; pack g 0..3 -> b128 store.
        if (quad == 0) {
            #pragma unroll
            for (int r = 0; r < 4; ++r) {
                f32x4 v = {acc[0][r], acc[1][r], acc[2][r], acc[3][r]};
                *(f32x4*)(scr_w + l15 * SSTRIDE + 4 * r) = v;
            }
        }

        // ---- elementwise: b=quad, unit u; one b128 gate read ----
        f32x4 g4 = *(const f32x4*)(scr_w + l15 * SSTRIDE + 4 * quad);

        const float gi = g4[0] + xcur * wih_s[0] + bias_s[0];
        const float gf = g4[1] + xcur * wih_s[1] + bias_s[1];
        const float gg = g4[2] + xcur * wih_s[2] + bias_s[2];
        const float go = g4[3] + xcur * wih_s[3] + bias_s[3];

        const float i_ = __builtin_amdgcn_rcpf(1.0f + __builtin_amdgcn_exp2f(gi));
        const float f_ = __builtin_amdgcn_rcpf(1.0f + __builtin_amdgcn_exp2f(gf));
        const float g_ = 2.0f * __builtin_amdgcn_rcpf(1.0f + __builtin_amdgcn_exp2f(gg)) - 1.0f;
        const float o_ = __builtin_amdgcn_rcpf(1.0f + __builtin_amdgcn_exp2f(go));

        c = f_ * c + i_ * g_;
        const float th = 2.0f * __builtin_amdgcn_rcpf(
                             1.0f + __builtin_amdgcn_exp2f((-2.0f * L2E) * c)) - 1.0f;
        const float h = o_ * th;

        // h write for next step's A-frags: row b=quad, col u
        h_buf[1 - p][quad * HSTRIDE + u] = (_Float16)h;
        xcur = xn;
        p ^= 1;
        __syncthreads();   // the ONLY barrier per step (h RAW; WAR safe via dbuf)
    }

    // ---------- fused FC head on final cell state (no activation) ----------
    // c layout: thread holds c(b=quad, u). Reuse scratch: c at [0..256), fc1 out at [256..768).
    float* c_lds  = scratch;
    float* h1_lds = scratch + 256;
    c_lds[quad * HID + u] = c;
    __syncthreads();

    for (int idx = tid; idx < MB * 128; idx += NTHR) {
        const int b = idx >> 7, j = idx & 127;
        const float* wrow = fc1_w + j * HID;
        const float* crow = c_lds + b * HID;
        float acc = fc1_b[j];
        #pragma unroll
        for (int k = 0; k < HID; k += 4)
            acc += crow[k] * wrow[k] + crow[k+1] * wrow[k+1]
                 + crow[k+2] * wrow[k+2] + crow[k+3] * wrow[k+3];
        h1_lds[idx] = acc;
    }
    __syncthreads();

    if (tid < MB * 5) {
        const int b = tid / 5, q = tid % 5;
        const float* wrow = fc2_w + q * 128;
        const float* hrow = h1_lds + b * 128;
        float acc = fc2_b[q];
        #pragma unroll 4
        for (int j = 0; j < 128; ++j) acc += hrow[j] * wrow[j];
        out[(b0 + b) * 5 + q] = acc;
    }
}

extern "C" void kernel_launch(void* const* d_in, const int* in_sizes, int n_in,
                              void* d_out, int out_size, void* d_ws, size_t ws_size,
                              hipStream_t stream) {
    const float* x     = (const float*)d_in[0];
    const float* W_ih  = (const float*)d_in[1];
    const float* W_hh  = (const float*)d_in[2];
    const float* b_ih  = (const float*)d_in[3];
    const float* b_hh  = (const float*)d_in[4];
    const float* fc1_w = (const float*)d_in[5];
    const float* fc1_b = (const float*)d_in[6];
    const float* fc2_w = (const float*)d_in[7];
    const float* fc2_b = (const float*)d_in[8];
    float* out = (float*)d_out;

    lstm_kernel<<<NBLK, NTHR, 0, stream>>>(x, W_ih, W_hh, b_ih, b_hh,
                                           fc1_w, fc1_b, fc2_w, fc2_b, out);
}

// Round 3
// 352.571 us; speedup vs baseline: 1.6801x; 1.6801x over previous
//
#include <hip/hip_runtime.h>
#include <hip/hip_bf16.h>

#define S_LEN 1024
#define BATCH 2048
#define HID   64
#define MB    4               // batch rows per block
#define NBLK  (BATCH / MB)    // 512 blocks -> 2 per CU
#define NTHR  (MB * HID)      // 256 threads = 4 waves

typedef _Float16 half8 __attribute__((ext_vector_type(8)));
typedef float    f32x4 __attribute__((ext_vector_type(4)));

#define L2E 1.4426950408889634f
#define HSTRIDE 72            // h row stride in halves (144 B)

__global__ __launch_bounds__(NTHR) void lstm_kernel(
    const float* __restrict__ x,      // (S, BATCH)
    const float* __restrict__ W_ih,   // (256,1)
    const float* __restrict__ W_hh,   // (256,64)
    const float* __restrict__ b_ih,   // (256,)
    const float* __restrict__ b_hh,   // (256,)
    const float* __restrict__ fc1_w,  // (128,64)
    const float* __restrict__ fc1_b,  // (128,)
    const float* __restrict__ fc2_w,  // (5,128)
    const float* __restrict__ fc2_b,  // (5,)
    float* __restrict__ out)          // (BATCH,5)
{
    // h double-buffered: only 4 real rows (batches), fp16
    __shared__ __align__(16) _Float16 h_buf[2][4 * HSTRIDE];    // 1152 B
    __shared__ __align__(16) float    head_lds[MB * HID + MB * 128]; // c + fc1 out

    const int tid  = threadIdx.x;
    const int lane = tid & 63;
    const int wave = tid >> 6;        // 0..3
    const int l15  = lane & 15;
    const int quad = lane >> 4;       // 0..3
    const int b0   = blockIdx.x * MB;

    // ---- zero both h buffers (h0 = 0) ----
    {
        unsigned* hz = (unsigned*)&h_buf[0][0];
        for (int i = tid; i < 2 * 4 * HSTRIDE / 2; i += NTHR) hz[i] = 0u;
    }

    // ---- stationary W_hh B-fragments, per-wave unit slice ----
    // wave w, gate g: frag col n=l15 <-> W_hh row g*64 + 16w + l15.
    // B-frag (16x16x32 f16): lane holds B[k=quad*8+j][n=l15]; k-tile kt adds 32.
    // Pre-scaled by -log2e (sigmoid) / -2log2e (tanh on g gate).
    half8 wfrag[4][2];
    #pragma unroll
    for (int g = 0; g < 4; ++g) {
        const float s = (g == 2) ? (-2.0f * L2E) : (-L2E);
        const float* wr = W_hh + (g * 64 + 16 * wave + l15) * HID + quad * 8;
        #pragma unroll
        for (int kt = 0; kt < 2; ++kt) {
            half8 f;
            #pragma unroll
            for (int j = 0; j < 8; ++j) f[j] = (_Float16)(wr[kt * 32 + j] * s);
            wfrag[g][kt] = f;
        }
    }

    // ---- elementwise ownership: thread (quad,l15) handles b=quad, u=16*wave+l15 ----
    const int u = 16 * wave + l15;
    float wih_s[4], bias_s[4];
    #pragma unroll
    for (int g = 0; g < 4; ++g) {
        const int n = g * 64 + u;
        const float s = (g == 2) ? (-2.0f * L2E) : (-L2E);
        wih_s[g]  = W_ih[n] * s;
        bias_s[g] = (b_ih[n] + b_hh[n]) * s;
    }

    const float* xcol = x + b0 + quad;   // this thread's batch row
    float xcur = xcol[0];
    float c = 0.0f;
    int p = 0;

    __syncthreads();

    for (int s = 0; s < S_LEN; ++s) {
        // prefetch next x early (latency hidden behind MFMA + elementwise)
        float xn = 0.0f;
        if (s + 1 < S_LEN) xn = xcol[(size_t)(s + 1) * BATCH];

        // ---- MFMA with replicated A: A[m][k] = h[m>>2][k] ----
        // => C[row=quad*4+r][col=l15] = gates[batch=quad][unit] for ALL r.
        // Lane (quad,l15) reads A row l15 := h[l15>>2] (same-address broadcast).
        const _Float16* arow = &h_buf[p][0] + (l15 >> 2) * HSTRIDE + quad * 8;
        half8 a0 = *(const half8*)(arow);        // k 0..31
        half8 a1 = *(const half8*)(arow + 32);   // k 32..63

        f32x4 acc[4];
        #pragma unroll
        for (int g = 0; g < 4; ++g) {
            f32x4 a = {0.f, 0.f, 0.f, 0.f};
            a = __builtin_amdgcn_mfma_f32_16x16x32_f16(a0, wfrag[g][0], a, 0, 0, 0);
            a = __builtin_amdgcn_mfma_f32_16x16x32_f16(a1, wfrag[g][1], a, 0, 0, 0);
            acc[g] = a;
        }

        // ---- elementwise: gates are register-resident in acc[g][0] ----
        const float gi = acc[0][0] + xcur * wih_s[0] + bias_s[0];
        const float gf = acc[1][0] + xcur * wih_s[1] + bias_s[1];
        const float gg = acc[2][0] + xcur * wih_s[2] + bias_s[2];
        const float go = acc[3][0] + xcur * wih_s[3] + bias_s[3];

        const float i_ = __builtin_amdgcn_rcpf(1.0f + __builtin_amdgcn_exp2f(gi));
        const float f_ = __builtin_amdgcn_rcpf(1.0f + __builtin_amdgcn_exp2f(gf));
        const float g_ = 2.0f * __builtin_amdgcn_rcpf(1.0f + __builtin_amdgcn_exp2f(gg)) - 1.0f;
        const float o_ = __builtin_amdgcn_rcpf(1.0f + __builtin_amdgcn_exp2f(go));

        c = f_ * c + i_ * g_;
        const float th = 2.0f * __builtin_amdgcn_rcpf(
                             1.0f + __builtin_amdgcn_exp2f((-2.0f * L2E) * c)) - 1.0f;
        const float h = o_ * th;

        // h for next step: row b=quad, col u (2-way b16 pairs -> free)
        h_buf[1 - p][quad * HSTRIDE + u] = (_Float16)h;
        xcur = xn;
        p ^= 1;
        __syncthreads();   // the ONLY barrier per step
    }

    // ---------- fused FC head on final cell state (no activation) ----------
    float* c_lds  = head_lds;            // 256 floats: [b][u]
    float* h1_lds = head_lds + MB * HID; // 512 floats: [b][j]
    c_lds[quad * HID + u] = c;
    __syncthreads();

    for (int idx = tid; idx < MB * 128; idx += NTHR) {
        const int b = idx >> 7, j = idx & 127;
        const float* wrow = fc1_w + j * HID;
        const float* crow = c_lds + b * HID;
        float acc = fc1_b[j];
        #pragma unroll
        for (int k = 0; k < HID; k += 4)
            acc += crow[k] * wrow[k] + crow[k+1] * wrow[k+1]
                 + crow[k+2] * wrow[k+2] + crow[k+3] * wrow[k+3];
        h1_lds[idx] = acc;
    }
    __syncthreads();

    if (tid < MB * 5) {
        const int b = tid / 5, q = tid % 5;
        const float* wrow = fc2_w + q * 128;
        const float* hrow = h1_lds + b * 128;
        float acc = fc2_b[q];
        #pragma unroll 4
        for (int j = 0; j < 128; ++j) acc += hrow[j] * wrow[j];
        out[(b0 + b) * 5 + q] = acc;
    }
}

extern "C" void kernel_launch(void* const* d_in, const int* in_sizes, int n_in,
                              void* d_out, int out_size, void* d_ws, size_t ws_size,
                              hipStream_t stream) {
    const float* x     = (const float*)d_in[0];
    const float* W_ih  = (const float*)d_in[1];
    const float* W_hh  = (const float*)d_in[2];
    const float* b_ih  = (const float*)d_in[3];
    const float* b_hh  = (const float*)d_in[4];
    const float* fc1_w = (const float*)d_in[5];
    const float* fc1_b = (const float*)d_in[6];
    const float* fc2_w = (const float*)d_in[7];
    const float* fc2_b = (const float*)d_in[8];
    float* out = (float*)d_out;

    lstm_kernel<<<NBLK, NTHR, 0, stream>>>(x, W_ih, W_hh, b_ih, b_hh,
                                           fc1_w, fc1_b, fc2_w, fc2_b, out);
}

// Round 4
// 341.466 us; speedup vs baseline: 1.7347x; 1.0325x over previous
//
#include <hip/hip_runtime.h>
#include <hip/hip_bf16.h>

#define S_LEN 1024
#define BATCH 2048
#define HID   64
#define MB    4               // batch rows per block
#define NBLK  (BATCH / MB)    // 512 blocks -> 2 per CU
#define NTHR  (MB * HID)      // 256 threads = 4 waves

typedef _Float16 half8 __attribute__((ext_vector_type(8)));
typedef float    f32x4 __attribute__((ext_vector_type(4)));

#define L2E 1.4426950408889634f
#define HSTRIDE 72            // h row stride in halves (144 B)

__global__ __launch_bounds__(NTHR) void lstm_kernel(
    const float* __restrict__ x,      // (S, BATCH)
    const float* __restrict__ W_ih,   // (256,1)
    const float* __restrict__ W_hh,   // (256,64)
    const float* __restrict__ b_ih,   // (256,)
    const float* __restrict__ b_hh,   // (256,)
    const float* __restrict__ fc1_w,  // (128,64)
    const float* __restrict__ fc1_b,  // (128,)
    const float* __restrict__ fc2_w,  // (5,128)
    const float* __restrict__ fc2_b,  // (5,)
    float* __restrict__ out)          // (BATCH,5)
{
    // h double-buffered: only 4 real rows (batches), fp16
    __shared__ __align__(16) _Float16 h_buf[2][4 * HSTRIDE];    // 1152 B
    __shared__ __align__(16) float    head_lds[MB * HID + MB * 128]; // c + fc1 out

    const int tid  = threadIdx.x;
    const int lane = tid & 63;
    const int wave = tid >> 6;        // 0..3
    const int l15  = lane & 15;
    const int quad = lane >> 4;       // 0..3
    const int b0   = blockIdx.x * MB;

    // ---- zero both h buffers (h0 = 0) ----
    {
        unsigned* hz = (unsigned*)&h_buf[0][0];
        for (int i = tid; i < 2 * 4 * HSTRIDE / 2; i += NTHR) hz[i] = 0u;
    }

    // ---- stationary W_hh B-fragments, per-wave unit slice ----
    // wave w, gate g: frag col n=l15 <-> W_hh row g*64 + 16w + l15.
    // B-frag (16x16x32 f16): lane holds B[k=quad*8+j][n=l15]; k-tile kt adds 32.
    // Pre-scaled by -log2e (sigmoid) / -2log2e (tanh on g gate).
    half8 wfrag[4][2];
    #pragma unroll
    for (int g = 0; g < 4; ++g) {
        const float s = (g == 2) ? (-2.0f * L2E) : (-L2E);
        const float* wr = W_hh + (g * 64 + 16 * wave + l15) * HID + quad * 8;
        #pragma unroll
        for (int kt = 0; kt < 2; ++kt) {
            half8 f;
            #pragma unroll
            for (int j = 0; j < 8; ++j) f[j] = (_Float16)(wr[kt * 32 + j] * s);
            wfrag[g][kt] = f;
        }
    }

    // ---- elementwise ownership: thread (quad,l15) handles b=quad, u=16*wave+l15 ----
    const int u = 16 * wave + l15;
    float wih_s[4], bias_s[4];
    #pragma unroll
    for (int g = 0; g < 4; ++g) {
        const int n = g * 64 + u;
        const float s = (g == 2) ? (-2.0f * L2E) : (-L2E);
        wih_s[g]  = W_ih[n] * s;
        bias_s[g] = (b_ih[n] + b_hh[n]) * s;
    }

    const float* xcol = x + b0 + quad;   // this thread's batch row
    float c = 0.0f;

    // ---- 4-deep x prefetch pipeline (hides L2/L3/HBM latency, ~4 steps slack) ----
    float xq[4];
    #pragma unroll
    for (int j = 0; j < 4; ++j) xq[j] = xcol[(size_t)j * BATCH];

    __syncthreads();

    // one unrolled body; hr/hw are the static double-buffer halves for this position
    auto body = [&](int base, int j, const _Float16* hr, _Float16* hw) {
        // consume this step's x, immediately refill the slot 4 steps ahead
        const float xv = xq[j];
        int sp = base + j + 4;                 // uniform
        if (sp > S_LEN - 1) sp = S_LEN - 1;    // clamp (value unused for tail steps)
        xq[j] = xcol[(size_t)sp * BATCH];

        // ---- MFMA with replicated A: A[m][k] = h[m>>2][k] ----
        // C[row=quad*4+r][col=l15] = gates[batch=quad][unit] for ALL r.
        const _Float16* arow = hr + (l15 >> 2) * HSTRIDE + quad * 8;
        half8 a0 = *(const half8*)(arow);        // k 0..31
        half8 a1 = *(const half8*)(arow + 32);   // k 32..63

        f32x4 acc[4];
        #pragma unroll
        for (int g = 0; g < 4; ++g) {
            f32x4 a = {0.f, 0.f, 0.f, 0.f};
            a = __builtin_amdgcn_mfma_f32_16x16x32_f16(a0, wfrag[g][0], a, 0, 0, 0);
            a = __builtin_amdgcn_mfma_f32_16x16x32_f16(a1, wfrag[g][1], a, 0, 0, 0);
            acc[g] = a;
        }

        // ---- elementwise: gates register-resident in acc[g][0] ----
        const float gi = acc[0][0] + __builtin_fmaf(xv, wih_s[0], bias_s[0]);
        const float gf = acc[1][0] + __builtin_fmaf(xv, wih_s[1], bias_s[1]);
        const float gg = acc[2][0] + __builtin_fmaf(xv, wih_s[2], bias_s[2]);
        const float go = acc[3][0] + __builtin_fmaf(xv, wih_s[3], bias_s[3]);

        const float i_ = __builtin_amdgcn_rcpf(1.0f + __builtin_amdgcn_exp2f(gi));
        const float f_ = __builtin_amdgcn_rcpf(1.0f + __builtin_amdgcn_exp2f(gf));
        const float g_ = 2.0f * __builtin_amdgcn_rcpf(1.0f + __builtin_amdgcn_exp2f(gg)) - 1.0f;
        const float o_ = __builtin_amdgcn_rcpf(1.0f + __builtin_amdgcn_exp2f(go));

        c = f_ * c + i_ * g_;
        const float th = 2.0f * __builtin_amdgcn_rcpf(
                             1.0f + __builtin_amdgcn_exp2f((-2.0f * L2E) * c)) - 1.0f;
        const float h = o_ * th;

        hw[quad * HSTRIDE + u] = (_Float16)h;
        __syncthreads();   // the ONLY barrier per step
    };

    _Float16* h0 = &h_buf[0][0];
    _Float16* h1 = &h_buf[1][0];

    for (int base = 0; base < S_LEN; base += 4) {
        body(base, 0, h0, h1);
        body(base, 1, h1, h0);
        body(base, 2, h0, h1);
        body(base, 3, h1, h0);
    }

    // ---------- fused FC head on final cell state (no activation) ----------
    float* c_lds  = head_lds;            // 256 floats: [b][u]
    float* h1_lds = head_lds + MB * HID; // 512 floats: [b][j]
    c_lds[quad * HID + u] = c;
    __syncthreads();

    for (int idx = tid; idx < MB * 128; idx += NTHR) {
        const int b = idx >> 7, j = idx & 127;
        const float* wrow = fc1_w + j * HID;
        const float* crow = c_lds + b * HID;
        float acc = fc1_b[j];
        #pragma unroll
        for (int k = 0; k < HID; k += 4)
            acc += crow[k] * wrow[k] + crow[k+1] * wrow[k+1]
                 + crow[k+2] * wrow[k+2] + crow[k+3] * wrow[k+3];
        h1_lds[idx] = acc;
    }
    __syncthreads();

    if (tid < MB * 5) {
        const int b = tid / 5, q = tid % 5;
        const float* wrow = fc2_w + q * 128;
        const float* hrow = h1_lds + b * 128;
        float acc = fc2_b[q];
        #pragma unroll 4
        for (int j = 0; j < 128; ++j) acc += hrow[j] * wrow[j];
        out[(b0 + b) * 5 + q] = acc;
    }
}

extern "C" void kernel_launch(void* const* d_in, const int* in_sizes, int n_in,
                              void* d_out, int out_size, void* d_ws, size_t ws_size,
                              hipStream_t stream) {
    const float* x     = (const float*)d_in[0];
    const float* W_ih  = (const float*)d_in[1];
    const float* W_hh  = (const float*)d_in[2];
    const float* b_ih  = (const float*)d_in[3];
    const float* b_hh  = (const float*)d_in[4];
    const float* fc1_w = (const float*)d_in[5];
    const float* fc1_b = (const float*)d_in[6];
    const float* fc2_w = (const float*)d_in[7];
    const float* fc2_b = (const float*)d_in[8];
    float* out = (float*)d_out;

    lstm_kernel<<<NBLK, NTHR, 0, stream>>>(x, W_ih, W_hh, b_ih, b_hh,
                                           fc1_w, fc1_b, fc2_w, fc2_b, out);
}